// Round 11
// baseline (372.146 us; speedup 1.0000x reference)
//
#include <hip/hip_runtime.h>
#include <cstdint>
#include <cmath>

#define F_INN 128
#define HIDD  128
#define NCLS  40

#define BUCK_SHIFT 7
#define BUCK_NODES 128
#define MAXBUCK 1024
#define NSPLIT 8
#define CHUNK 8192

typedef unsigned int u32;
typedef unsigned short u16;
typedef __attribute__((ext_vector_type(8))) short bf16x8;
typedef __attribute__((ext_vector_type(4))) float f32x4;

static __device__ __forceinline__ float bflo(u32 u) { return __builtin_bit_cast(float, u << 16); }
static __device__ __forceinline__ float bfhi(u32 u) { return __builtin_bit_cast(float, u & 0xffff0000u); }
static __device__ __forceinline__ u16 f2bf(float f) {
    u32 u = __builtin_bit_cast(u32, f);
    return (u16)((u + 0x7fffu + ((u >> 16) & 1u)) >> 16);
}
static __device__ __forceinline__ u32 pack2(float a, float b) {
    return (u32)f2bf(a) | ((u32)f2bf(b) << 16);
}

// ---------------- S1: per-chunk bucket histogram -> per-(bucket,slot) totals ----------------

__global__ __launch_bounds__(256) void k_s1(const int* __restrict__ ei, u32* __restrict__ gtot,
                                            int E, int nbuck) {
    __shared__ u32 cnt[MAXBUCK];
    int t = threadIdx.x;
    for (int i = t; i < nbuck; i += 256) cnt[i] = 0;
    __syncthreads();
    int x = blockIdx.x & (NSPLIT - 1);
    int e0 = blockIdx.x * CHUNK;
    int n = min(CHUNK, E - e0);
    const int* dst = ei + E;
    for (int i = t; i < n; i += 256)
        atomicAdd(&cnt[dst[e0 + i] >> BUCK_SHIFT], 1u);
    __syncthreads();
    for (int b = t; b < nbuck; b += 256) {
        u32 c = cnt[b];
        if (c) atomicAdd(&gtot[(b << 3) | x], c);
    }
}

// ---------------- S2: exclusive scan ----------------

__global__ __launch_bounds__(256) void k_s2(const u32* __restrict__ gtot, u32* __restrict__ base,
                                            u32* __restrict__ cursor, int m) {
    __shared__ u32 part[256];
    int t = threadIdx.x;
    u32 local[32];
    u32 s = 0;
#pragma unroll
    for (int j = 0; j < 32; ++j) {
        int i = t * 32 + j;
        u32 v = (i < m) ? gtot[i] : 0u;
        local[j] = s;
        s += v;
    }
    part[t] = s;
    __syncthreads();
    for (int off = 1; off < 256; off <<= 1) {
        u32 v = (t >= off) ? part[t - off] : 0u;
        __syncthreads();
        part[t] += v;
        __syncthreads();
    }
    u32 pre = (t == 0) ? 0u : part[t - 1];
#pragma unroll
    for (int j = 0; j < 32; ++j) {
        int i = t * 32 + j;
        if (i < m) { u32 bb = pre + local[j]; base[i] = bb; cursor[i] = bb; }
    }
    if (t == 255) base[m] = part[255];
}

// ---------------- S3: scatter packed edges into bucket sub-windows ----------------

__global__ __launch_bounds__(256) void k_s3(const int* __restrict__ ei, u32* __restrict__ cursor,
                                            u32* __restrict__ arr, int E, int nbuck) {
    __shared__ u32 cnt[MAXBUCK];
    __shared__ u32 lbase[MAXBUCK];
    int t = threadIdx.x;
    for (int i = t; i < nbuck; i += 256) cnt[i] = 0;
    __syncthreads();
    int x = blockIdx.x & (NSPLIT - 1);
    int e0 = blockIdx.x * CHUNK;
    int n = min(CHUNK, E - e0);
    const int* src = ei;
    const int* dst = ei + E;
    for (int i = t; i < n; i += 256)
        atomicAdd(&cnt[dst[e0 + i] >> BUCK_SHIFT], 1u);
    __syncthreads();
    for (int b = t; b < nbuck; b += 256) {
        u32 c = cnt[b];
        lbase[b] = c ? atomicAdd(&cursor[(b << 3) | x], c) : 0u;
    }
    __syncthreads();
    for (int i = t; i < nbuck; i += 256) cnt[i] = 0;
    __syncthreads();
    for (int i = t; i < n; i += 256) {
        int s = src[e0 + i], d = dst[e0 + i];
        int b = d >> BUCK_SHIFT;
        u32 off = atomicAdd(&cnt[b], 1u);
        arr[lbase[b] + off] = ((u32)s << BUCK_SHIFT) | (u32)(d & (BUCK_NODES - 1));
    }
}

// ---------------- SORT: per-bucket counting sort -> dense csr + rowptr + dinv ----------------

__global__ __launch_bounds__(256) void k_sortb(const u32* __restrict__ arr, const u32* __restrict__ base,
                                               int* __restrict__ csr, int* __restrict__ rowptr,
                                               float* __restrict__ dinv, int N, int nbuck) {
    __shared__ u32 cnt[BUCK_NODES];
    __shared__ u32 ex[BUCK_NODES];
    __shared__ u32 cur[BUCK_NODES];
    int b = blockIdx.x, t = threadIdx.x;
    int node0 = b << BUCK_SHIFT;
    if (t < BUCK_NODES) cnt[t] = 0;
    __syncthreads();
    u32 s0 = base[b << 3], s1 = base[(b + 1) << 3];
    for (u32 i = s0 + t; i < s1; i += 256)
        atomicAdd(&cnt[arr[i] & (u32)(BUCK_NODES - 1)], 1u);
    __syncthreads();
    if (t < BUCK_NODES) ex[t] = cnt[t];
    __syncthreads();
    for (int off = 1; off < BUCK_NODES; off <<= 1) {
        u32 v = 0;
        if (t < BUCK_NODES && t >= off) v = ex[t - off];
        __syncthreads();
        if (t < BUCK_NODES) ex[t] += v;
        __syncthreads();
    }
    if (t < BUCK_NODES) {
        int node = node0 + t;
        u32 excl = ex[t] - cnt[t];
        cur[t] = s0 + excl;
        if (node <= N) rowptr[node] = (int)(s0 + excl);
        if (node < N) dinv[node] = rsqrtf((float)(cnt[t] + 1));
    }
    if (t == 0 && b == nbuck - 1) rowptr[N] = (int)s1;
    __syncthreads();
    for (u32 i = s0 + t; i < s1; i += 256) {
        u32 pk = arr[i];
        int d = (int)(pk & (u32)(BUCK_NODES - 1));
        u32 pos = atomicAdd(&cur[d], 1u);
        csr[pos] = (int)(pk >> BUCK_SHIFT);
    }
}

// ---------------- GEMM1 (MFMA): H1' = bf16( dinv[r] * (X @ W1) ) ----------------

__global__ __launch_bounds__(256) void k_gemm1m(const float* __restrict__ X, const float* __restrict__ W,
                                                const float* __restrict__ dinv,
                                                u32* __restrict__ H, int M) {
    __shared__ u32 xa[128 * 64];
    __shared__ u32 wb[128 * 64];
    int tid = threadIdx.x;
    int row0 = blockIdx.x * 128;
    for (int j = tid; j < 64 * 128; j += 256) {
        int n = j & 127, kp = j >> 7;
        u32 v = pack2(W[(2 * kp) * 128 + n], W[(2 * kp + 1) * 128 + n]);
        wb[n * 64 + (kp ^ ((n & 7) << 2))] = v;
    }
    for (int j = tid; j < 128 * 64; j += 256) {
        int r = j >> 6, c = j & 63;
        int gr = row0 + r;
        u32 v = 0;
        if (gr < M) {
            float2 xv = *(const float2*)&X[(size_t)gr * 128 + 2 * c];
            v = pack2(xv.x, xv.y);
        }
        xa[r * 64 + (c ^ ((r & 7) << 2))] = v;
    }
    __syncthreads();
    int lane = tid & 63, wv = tid >> 6;
    int rw = wv * 32;
    int lr = lane & 15, lg = lane >> 4;
    f32x4 acc[2][8] = {};
    for (int kk = 0; kk < 4; ++kk) {
        int c0 = kk * 16 + lg * 4;
        int ra0 = rw + lr, ra1 = rw + 16 + lr;
        bf16x8 a0 = *(const bf16x8*)&xa[ra0 * 64 + (c0 ^ ((ra0 & 7) << 2))];
        bf16x8 a1 = *(const bf16x8*)&xa[ra1 * 64 + (c0 ^ ((ra1 & 7) << 2))];
#pragma unroll
        for (int nf = 0; nf < 8; ++nf) {
            int bn = nf * 16 + lr;
            bf16x8 bfr = *(const bf16x8*)&wb[bn * 64 + (c0 ^ ((bn & 7) << 2))];
            acc[0][nf] = __builtin_amdgcn_mfma_f32_16x16x32_bf16(a0, bfr, acc[0][nf], 0, 0, 0);
            acc[1][nf] = __builtin_amdgcn_mfma_f32_16x16x32_bf16(a1, bfr, acc[1][nf], 0, 0, 0);
        }
    }
    float drow[2][4];
#pragma unroll
    for (int rf = 0; rf < 2; ++rf)
#pragma unroll
        for (int j = 0; j < 4; ++j) {
            int gr = row0 + rw + rf * 16 + lg * 4 + j;
            drow[rf][j] = (gr < M) ? dinv[gr] : 0.f;
        }
    u16* Hs = (u16*)H;
#pragma unroll
    for (int rf = 0; rf < 2; ++rf) {
#pragma unroll
        for (int nf = 0; nf < 8; ++nf) {
            int col = nf * 16 + lr;
#pragma unroll
            for (int j = 0; j < 4; ++j) {
                int gr = row0 + rw + rf * 16 + lg * 4 + j;
                if (gr < M) Hs[(size_t)gr * 128 + col] = f2bf(acc[rf][nf][j] * drow[rf][j]);
            }
        }
    }
}

// ---------------- GEMM2 (MFMA): H2' = bf16( A1' @ W2 ) ----------------

__global__ __launch_bounds__(256) void k_gemm2m(const u32* __restrict__ A, const float* __restrict__ W,
                                                u32* __restrict__ H, int M) {
    __shared__ u32 xa[128 * 64];
    __shared__ u32 wb[48 * 64];
    int tid = threadIdx.x;
    int row0 = blockIdx.x * 128;
    for (int j = tid; j < 64 * 64; j += 256) {
        int n = j & 63, kp = j >> 6;
        if (n < 48) {
            u32 v = 0;
            if (n < 40) v = pack2(W[(2 * kp) * 40 + n], W[(2 * kp + 1) * 40 + n]);
            wb[n * 64 + (kp ^ ((n & 7) << 2))] = v;
        }
    }
    for (int j = tid; j < 128 * 64; j += 256) {
        int r = j >> 6, c = j & 63;
        int gr = row0 + r;
        u32 v = (gr < M) ? A[(size_t)gr * 64 + c] : 0u;
        xa[r * 64 + (c ^ ((r & 7) << 2))] = v;
    }
    __syncthreads();
    int lane = tid & 63, wv = tid >> 6;
    int rw = wv * 32;
    int lr = lane & 15, lg = lane >> 4;
    f32x4 acc[2][3] = {};
    for (int kk = 0; kk < 4; ++kk) {
        int c0 = kk * 16 + lg * 4;
        int ra0 = rw + lr, ra1 = rw + 16 + lr;
        bf16x8 a0 = *(const bf16x8*)&xa[ra0 * 64 + (c0 ^ ((ra0 & 7) << 2))];
        bf16x8 a1 = *(const bf16x8*)&xa[ra1 * 64 + (c0 ^ ((ra1 & 7) << 2))];
#pragma unroll
        for (int nf = 0; nf < 3; ++nf) {
            int bn = nf * 16 + lr;
            bf16x8 bfr = *(const bf16x8*)&wb[bn * 64 + (c0 ^ ((bn & 7) << 2))];
            acc[0][nf] = __builtin_amdgcn_mfma_f32_16x16x32_bf16(a0, bfr, acc[0][nf], 0, 0, 0);
            acc[1][nf] = __builtin_amdgcn_mfma_f32_16x16x32_bf16(a1, bfr, acc[1][nf], 0, 0, 0);
        }
    }
    u16* Hs = (u16*)H;
#pragma unroll
    for (int rf = 0; rf < 2; ++rf) {
#pragma unroll
        for (int nf = 0; nf < 3; ++nf) {
            int col = nf * 16 + lr;
            if (col < 40) {
#pragma unroll
                for (int j = 0; j < 4; ++j) {
                    int gr = row0 + rw + rf * 16 + lg * 4 + j;
                    if (gr < M) Hs[(size_t)gr * 64 + col] = f2bf(acc[rf][nf][j]);
                }
            }
        }
    }
}

// ---------------- AGG1 (pull, half-wave uint2, unroll 8): A1' = dinv*relu(dinv*Sum + b1) ----------------
// lane = (half, c): half processes even/odd edge stream; lane loads uint2 (8B) of the row.
// One load instruction covers 2 edges (vs 1 before) -> half the load-issue cost.

__global__ __launch_bounds__(256) void k_agg1(const u32* __restrict__ H1, const int* __restrict__ csr,
                                              const int* __restrict__ rowptr, const float* __restrict__ dinv,
                                              const float* __restrict__ b1, u32* __restrict__ A1, int n) {
    int node = (int)((blockIdx.x * 256 + threadIdx.x) >> 6);
    int lane = threadIdx.x & 63;
    if (node >= n) return;
    int half = lane >> 5;
    int c = lane & 31;                     // u32-pair index: u32s 2c, 2c+1 (features 4c..4c+3)
    float di = dinv[node];
    float a0 = 0.f, a1 = 0.f, a2 = 0.f, a3 = 0.f;
    if (half == 0) {                       // self term counted once
        uint2 us = *(const uint2*)&H1[(size_t)node * 64 + 2 * c];
        a0 = bflo(us.x); a1 = bfhi(us.x); a2 = bflo(us.y); a3 = bfhi(us.y);
    }
    int e0 = rowptr[node], e1 = rowptr[node + 1];
    int e = e0 + half;
    for (; e + 14 < e1; e += 16) {
        int s0 = csr[e],      s1 = csr[e + 2],  s2 = csr[e + 4],  s3 = csr[e + 6];
        int s4 = csr[e + 8],  s5 = csr[e + 10], s6 = csr[e + 12], s7 = csr[e + 14];
        uint2 u0 = *(const uint2*)&H1[(size_t)s0 * 64 + 2 * c];
        uint2 u1 = *(const uint2*)&H1[(size_t)s1 * 64 + 2 * c];
        uint2 u2 = *(const uint2*)&H1[(size_t)s2 * 64 + 2 * c];
        uint2 u3 = *(const uint2*)&H1[(size_t)s3 * 64 + 2 * c];
        uint2 u4 = *(const uint2*)&H1[(size_t)s4 * 64 + 2 * c];
        uint2 u5 = *(const uint2*)&H1[(size_t)s5 * 64 + 2 * c];
        uint2 u6 = *(const uint2*)&H1[(size_t)s6 * 64 + 2 * c];
        uint2 u7 = *(const uint2*)&H1[(size_t)s7 * 64 + 2 * c];
        a0 += ((bflo(u0.x) + bflo(u1.x)) + (bflo(u2.x) + bflo(u3.x)))
            + ((bflo(u4.x) + bflo(u5.x)) + (bflo(u6.x) + bflo(u7.x)));
        a1 += ((bfhi(u0.x) + bfhi(u1.x)) + (bfhi(u2.x) + bfhi(u3.x)))
            + ((bfhi(u4.x) + bfhi(u5.x)) + (bfhi(u6.x) + bfhi(u7.x)));
        a2 += ((bflo(u0.y) + bflo(u1.y)) + (bflo(u2.y) + bflo(u3.y)))
            + ((bflo(u4.y) + bflo(u5.y)) + (bflo(u6.y) + bflo(u7.y)));
        a3 += ((bfhi(u0.y) + bfhi(u1.y)) + (bfhi(u2.y) + bfhi(u3.y)))
            + ((bfhi(u4.y) + bfhi(u5.y)) + (bfhi(u6.y) + bfhi(u7.y)));
    }
    for (; e < e1; e += 2) {
        int s = csr[e];
        uint2 u = *(const uint2*)&H1[(size_t)s * 64 + 2 * c];
        a0 += bflo(u.x); a1 += bfhi(u.x); a2 += bflo(u.y); a3 += bfhi(u.y);
    }
    a0 += __shfl_xor(a0, 32, 64);
    a1 += __shfl_xor(a1, 32, 64);
    a2 += __shfl_xor(a2, 32, 64);
    a3 += __shfl_xor(a3, 32, 64);
    if (half == 0) {
        float4 bb = *(const float4*)&b1[4 * c];
        a0 = fmaxf(di * a0 + bb.x, 0.f) * di;
        a1 = fmaxf(di * a1 + bb.y, 0.f) * di;
        a2 = fmaxf(di * a2 + bb.z, 0.f) * di;
        a3 = fmaxf(di * a3 + bb.w, 0.f) * di;
        uint2 o; o.x = pack2(a0, a1); o.y = pack2(a2, a3);
        *(uint2*)&A1[(size_t)node * 64 + 2 * c] = o;
    }
}

// ---------------- AGG2 (pull, dual-edge uint2) + bias + log_softmax ----------------
// 2 nodes/wave (32-lane halves). Within a half: lanes 0-9 = edge e, lanes 10-19 = edge e+1,
// each lane loads uint2 (4 classes). Combine via shfl(lane+10); softmax over 10 lanes x 4.

__global__ __launch_bounds__(256) void k_agg2(const u32* __restrict__ H2, const int* __restrict__ csr,
                                              const int* __restrict__ rowptr, const float* __restrict__ dinv,
                                              const float* __restrict__ b2, float* __restrict__ out, int n) {
    int wid = (int)((blockIdx.x * 256 + threadIdx.x) >> 6);
    int lane = threadIdx.x & 63;
    int half = lane >> 5, l = lane & 31;
    int node = wid * 2 + half;
    int nc = (node < n) ? node : (n - 1);
    bool act = l < 20;
    int sub = act ? (l / 10) : 0;
    int c = act ? (l % 10) : 0;            // u32-pair: u32s 2c,2c+1 = classes 4c..4c+3
    float di = dinv[nc];
    float a0 = 0.f, a1 = 0.f, a2 = 0.f, a3 = 0.f;
    if (act && sub == 0) {                 // self term once
        uint2 us = *(const uint2*)&H2[(size_t)nc * 32 + 2 * c];
        a0 = bflo(us.x); a1 = bfhi(us.x); a2 = bflo(us.y); a3 = bfhi(us.y);
    }
    int e0 = rowptr[nc], e1 = rowptr[nc + 1];
    if (act) {
        int e = e0 + sub;
        for (; e + 6 < e1; e += 8) {
            int s0 = csr[e], s1 = csr[e + 2], s2 = csr[e + 4], s3 = csr[e + 6];
            uint2 u0 = *(const uint2*)&H2[(size_t)s0 * 32 + 2 * c];
            uint2 u1 = *(const uint2*)&H2[(size_t)s1 * 32 + 2 * c];
            uint2 u2 = *(const uint2*)&H2[(size_t)s2 * 32 + 2 * c];
            uint2 u3 = *(const uint2*)&H2[(size_t)s3 * 32 + 2 * c];
            a0 += (bflo(u0.x) + bflo(u1.x)) + (bflo(u2.x) + bflo(u3.x));
            a1 += (bfhi(u0.x) + bfhi(u1.x)) + (bfhi(u2.x) + bfhi(u3.x));
            a2 += (bflo(u0.y) + bflo(u1.y)) + (bflo(u2.y) + bflo(u3.y));
            a3 += (bfhi(u0.y) + bfhi(u1.y)) + (bfhi(u2.y) + bfhi(u3.y));
        }
        for (; e < e1; e += 2) {
            int s = csr[e];
            uint2 u = *(const uint2*)&H2[(size_t)s * 32 + 2 * c];
            a0 += bflo(u.x); a1 += bfhi(u.x); a2 += bflo(u.y); a3 += bfhi(u.y);
        }
    }
    // fold sub1 (lanes 10-19) into sub0 (lanes 0-9)
    a0 += __shfl(a0, lane + 10, 64);
    a1 += __shfl(a1, lane + 10, 64);
    a2 += __shfl(a2, lane + 10, 64);
    a3 += __shfl(a3, lane + 10, 64);
    bool fin = (l < 10);
    float m4 = -INFINITY;
    if (fin) {
        float4 bb = *(const float4*)&b2[4 * c];
        a0 = di * a0 + bb.x;
        a1 = di * a1 + bb.y;
        a2 = di * a2 + bb.z;
        a3 = di * a3 + bb.w;
        m4 = fmaxf(fmaxf(a0, a1), fmaxf(a2, a3));
    }
    float v = m4;
#pragma unroll
    for (int off = 16; off > 0; off >>= 1) v = fmaxf(v, __shfl_xor(v, off, 64));
    float ex = fin ? (expf(a0 - v) + expf(a1 - v) + expf(a2 - v) + expf(a3 - v)) : 0.f;
#pragma unroll
    for (int off = 16; off > 0; off >>= 1) ex += __shfl_xor(ex, off, 64);
    float ls = logf(ex);
    if (fin && node < n) {
        float4 o;
        o.x = a0 - v - ls; o.y = a1 - v - ls; o.z = a2 - v - ls; o.w = a3 - v - ls;
        *(float4*)&out[(size_t)node * NCLS + 4 * c] = o;
    }
}

// ---------------- launch ----------------

extern "C" void kernel_launch(void* const* d_in, const int* in_sizes, int n_in,
                              void* d_out, int out_size, void* d_ws, size_t ws_size,
                              hipStream_t stream) {
    const float* X  = (const float*)d_in[0];
    const int*   EI = (const int*)d_in[1];
    const float* W1 = (const float*)d_in[2];
    const float* B1 = (const float*)d_in[3];
    const float* W2 = (const float*)d_in[4];
    const float* B2 = (const float*)d_in[5];
    float* OUT = (float*)d_out;

    const int N = in_sizes[0] / F_INN;        // 100000
    const int E = in_sizes[1] / 2;            // 1600000
    const int nbuck = (N + BUCK_NODES - 1) >> BUCK_SHIFT;   // 782
    const int m = nbuck * NSPLIT;

    char* ws = (char*)d_ws;
    size_t off = 0;
    auto alloc = [&](size_t bytes) -> void* {
        off = (off + 255) & ~(size_t)255;
        void* p = ws + off;
        off += bytes;
        return p;
    };
    u32*   H1     = (u32*)  alloc((size_t)N * 64 * 4);
    u32*   A1     = (u32*)  alloc((size_t)N * 64 * 4);
    u32*   H2     = (u32*)  alloc((size_t)N * 32 * 4);
    float* dinv   = (float*)alloc((size_t)N * 4);
    u32*   gtot   = (u32*)  alloc((size_t)(m + 1) * 4);
    u32*   base   = (u32*)  alloc((size_t)(m + 1) * 4);
    u32*   cursor = (u32*)  alloc((size_t)m * 4);
    u32*   arr    = (u32*)  alloc((size_t)E * 4);
    int*   csr    = (int*)  alloc((size_t)E * 4);
    int*   rowptr = (int*)  alloc((size_t)(N + 1) * 4);

    hipMemsetAsync(gtot, 0, (size_t)m * 4, stream);

    int nchunk = (E + CHUNK - 1) / CHUNK;

    k_s1   <<<nchunk, 256, 0, stream>>>(EI, gtot, E, nbuck);
    k_s2   <<<1, 256, 0, stream>>>(gtot, base, cursor, m);
    k_s3   <<<nchunk, 256, 0, stream>>>(EI, cursor, arr, E, nbuck);
    k_sortb<<<nbuck, 256, 0, stream>>>(arr, base, csr, rowptr, dinv, N, nbuck);

    int gblk = (N + 127) / 128;               // 782
    k_gemm1m<<<gblk, 256, 0, stream>>>(X, W1, dinv, H1, N);
    k_agg1  <<<(N + 3) / 4, 256, 0, stream>>>(H1, csr, rowptr, dinv, B1, A1, N);
    k_gemm2m<<<gblk, 256, 0, stream>>>(A1, W2, H2, N);
    int nw = (N + 1) / 2;
    k_agg2  <<<(nw + 3) / 4, 256, 0, stream>>>(H2, csr, rowptr, dinv, B2, OUT, N);
}